// Round 1
// baseline (87.850 us; speedup 1.0000x reference)
//
#include <hip/hip_runtime.h>

// AssignYolo: N=262144 anchors, M=128 gts, THRESH=0.3
// Layout: 256-thread blocks = 4 waves; each wave handles 64 consecutive anchors
// (wave-uniform anchor load -> broadcast). Lane l owns gt[l] and gt[l+64], so the
// per-gt argmax needs no cross-lane reduction; the row threshold is one ballot
// per anchor. Division is default (IEEE correctly-rounded) f32 to bitwise-match
// the numpy reference's rounded quotients; argmax tie-break = smallest anchor
// index via packed key (iou_bits<<32)|(~idx).

static __device__ __forceinline__ unsigned long long umax64(unsigned long long a,
                                                            unsigned long long b) {
    return a > b ? a : b;
}

static __device__ __forceinline__ unsigned long long packbest(float iou, unsigned idx) {
    // iou >= 0 always (inter>=0, union>0), so float bits are monotone as u32.
    // Low word = 0xFFFFFFFF - idx: ties in iou resolve to the SMALLEST index,
    // matching jnp.argmax(axis=0) first-occurrence semantics.
    return ((unsigned long long)__float_as_uint(iou) << 32)
         | (unsigned long long)(0xFFFFFFFFu - idx);
}

template <int USE_ATOMIC>
__global__ __launch_bounds__(256) void k_main(const float4* __restrict__ anchors,
                                              const float4* __restrict__ gt,
                                              int* __restrict__ assign,
                                              unsigned long long* __restrict__ bb,
                                              int nblocks) {
    const int lane = threadIdx.x & 63;
    const int wave = threadIdx.x >> 6;

    // Each lane owns two gts: lane and lane+64 (M == 128).
    const float4 g0 = gt[lane];
    const float4 g1 = gt[lane + 64];
    const float ga0 = (g0.z - g0.x) * (g0.w - g0.y);
    const float ga1 = (g1.z - g1.x) * (g1.w - g1.y);

    const int base = (blockIdx.x * 4 + wave) * 64;

    // Per-lane column best. Init (iou=0, idx=0) reproduces argmax-of-all-zeros -> 0.
    float bi0 = 0.0f, bi1 = 0.0f;
    unsigned bx0 = 0u, bx1 = 0u;
    unsigned long long rowmask = 0ull;  // wave-uniform: bit j = anchor base+j has iou>=0.3

#pragma unroll 8
    for (int j = 0; j < 64; ++j) {
        const int aj = base + j;
        const float4 a = anchors[aj];  // wave-uniform address -> broadcast

        float w0 = fmaxf(fminf(a.z, g0.z) - fmaxf(a.x, g0.x), 0.0f);
        float h0 = fmaxf(fminf(a.w, g0.w) - fmaxf(a.y, g0.y), 0.0f);
        float w1 = fmaxf(fminf(a.z, g1.z) - fmaxf(a.x, g1.x), 0.0f);
        float h1 = fmaxf(fminf(a.w, g1.w) - fmaxf(a.y, g1.y), 0.0f);
        float in0 = w0 * h0;
        float in1 = w1 * h1;

        // ~31% of anchors overlap no gt at all across the whole wave: skip the
        // expensive correctly-rounded divisions in that case (wave-uniform branch).
        if (__ballot((in0 > 0.0f) || (in1 > 0.0f)) != 0ull) {
            float aa = (a.z - a.x) * (a.w - a.y);
            // Order of ops matches reference: (area_a + area_g) - inter, then /.
            float iou0 = in0 / ((aa + ga0) - in0);
            float iou1 = in1 / ((aa + ga1) - in1);
            // Strictly-greater keeps the earliest index within a lane (j ascending).
            if (iou0 > bi0) { bi0 = iou0; bx0 = (unsigned)aj; }
            if (iou1 > bi1) { bi1 = iou1; bx1 = (unsigned)aj; }
            unsigned long long rb = __ballot((iou0 >= 0.3f) || (iou1 >= 0.3f));
            if (rb != 0ull) rowmask |= (1ull << j);
        }
    }

    // Coalesced row-result store: lane l writes anchor base+l using bit l.
    assign[base + lane] = ((rowmask >> lane) & 1ull) ? -2 : -1;

    // Reduce the 4 waves' per-gt bests via LDS.
    __shared__ unsigned long long red[4][128];
    red[wave][lane] = packbest(bi0, bx0);
    red[wave][lane + 64] = packbest(bi1, bx1);
    __syncthreads();

    const int t = threadIdx.x;
    if (t < 128) {
        unsigned long long m = umax64(umax64(red[0][t], red[1][t]),
                                      umax64(red[2][t], red[3][t]));
        if (USE_ATOMIC) {
            atomicMax(&bb[t], m);
        } else {
            bb[(size_t)t * nblocks + blockIdx.x] = m;  // [gt][block]
        }
    }
}

// Path A phase 2: reduce per-block partials for one gt per block, then claim.
__global__ __launch_bounds__(256) void k_reduce(const unsigned long long* __restrict__ bb,
                                                int* __restrict__ assign, int nblocks) {
    const int g = blockIdx.x;
    const unsigned long long* row = bb + (size_t)g * nblocks;
    unsigned long long m = 0ull;
    for (int i = threadIdx.x; i < nblocks; i += 256) m = umax64(m, row[i]);
    __shared__ unsigned long long s[256];
    s[threadIdx.x] = m;
    __syncthreads();
#pragma unroll
    for (int off = 128; off > 0; off >>= 1) {
        if (threadIdx.x < off) s[threadIdx.x] = umax64(s[threadIdx.x], s[threadIdx.x + off]);
        __syncthreads();
    }
    if (threadIdx.x == 0) {
        unsigned idx = 0xFFFFFFFFu - (unsigned)(s[0] & 0xFFFFFFFFull);
        // gt ids >= 0 > {-1,-2}; duplicate claims resolved by max (higher gt wins),
        // exactly matching assign.at[col_arg].max(arange(M)).
        atomicMax(assign + idx, g);
    }
}

// Path B (small-ws fallback): init packed bests, then finalize from 128 slots.
__global__ void k_init(unsigned long long* bb) {
    bb[threadIdx.x] = packbest(0.0f, 0u);
}

__global__ void k_final(const unsigned long long* __restrict__ bb, int* __restrict__ assign) {
    const int g = threadIdx.x;
    unsigned idx = 0xFFFFFFFFu - (unsigned)(bb[g] & 0xFFFFFFFFull);
    atomicMax(assign + idx, g);
}

extern "C" void kernel_launch(void* const* d_in, const int* in_sizes, int n_in,
                              void* d_out, int out_size, void* d_ws, size_t ws_size,
                              hipStream_t stream) {
    const float4* anchors = (const float4*)d_in[0];
    const float4* gt = (const float4*)d_in[1];
    int* assign = (int*)d_out;  // reference output dtype is int32

    const int n = in_sizes[0] / 4;       // 262144
    const int nblocks = n / 256;         // 1024 (n is a multiple of 256)

    unsigned long long* bb = (unsigned long long*)d_ws;
    const size_t needA = (size_t)128 * (size_t)nblocks * sizeof(unsigned long long);

    if (ws_size >= needA) {
        k_main<0><<<nblocks, 256, 0, stream>>>(anchors, gt, assign, bb, nblocks);
        k_reduce<<<128, 256, 0, stream>>>(bb, assign, nblocks);
    } else {
        k_init<<<1, 128, 0, stream>>>(bb);
        k_main<1><<<nblocks, 256, 0, stream>>>(anchors, gt, assign, bb, nblocks);
        k_final<<<1, 128, 0, stream>>>(bb, assign);
    }
}